// Round 4
// baseline (761.668 us; speedup 1.0000x reference)
//
#include <hip/hip_runtime.h>

#define TOKENS 8192
#define HIDDEN 2048
#define INTER  5632

typedef _Float16 f16x8 __attribute__((ext_vector_type(8)));
typedef _Float16 f16x2 __attribute__((ext_vector_type(2)));
typedef float    f32x4 __attribute__((ext_vector_type(4)));

// async global->LDS, 16B per lane. LDS dest = wave-uniform base + lane*16.
__device__ __forceinline__ void async_copy16(const void* g, void* l) {
  __builtin_amdgcn_global_load_lds(
      (const __attribute__((address_space(1))) unsigned int*)g,
      (__attribute__((address_space(3))) unsigned int*)l, 16, 0, 0);
}

#define BAR   __builtin_amdgcn_s_barrier()
#define SB0   __builtin_amdgcn_sched_barrier(0)
#define LGKM0 do { asm volatile("s_waitcnt lgkmcnt(0)" ::: "memory"); SB0; } while (0)
#define WAITVM(n) asm volatile("s_waitcnt vmcnt(" #n ")" ::: "memory")
#define PRIO(x) __builtin_amdgcn_s_setprio(x)

// GPTQ int4 -> f16x8 dequant, magic-bias pk form.
// q nibbles j at bits 4j. r.u[j] = {1024+nib_j , 1024+nib_{j+4}} via 0x6400 OR.
// d = (h - c2) is EXACT (integers <= 1040 in f16); w = d*s2 single rounding.
// Output k-order is [0,4,1,5,2,6,3,7] -- A operand staged with same permutation.
__device__ __forceinline__ f16x8 dq8(unsigned int q, f16x2 s2, f16x2 c2) {
  union { unsigned int u[4]; f16x8 v; } r;
#pragma unroll
  for (int j = 0; j < 4; ++j) {
    const unsigned int t = ((q >> (4 * j)) & 0x000F000Fu) | 0x64006400u;
    f16x2 h = __builtin_bit_cast(f16x2, t);
    h = (h - c2) * s2;
    r.u[j] = __builtin_bit_cast(unsigned int, h);
  }
  return r.v;
}

// ---------------- producers ----------------

// x [T,H] fp32 -> staged [T/128][H/8][128][8] f16, k-order permuted [0,4,1,5,2,6,3,7]
// within each 8-group to match dq8's output order (dot product is perm-invariant
// when both operands share the permutation).
__global__ __launch_bounds__(256)
void k_convert_x(const float* __restrict__ x, _Float16* __restrict__ xs) {
  __shared__ float lt[64 * 33];
  const int kb0  = blockIdx.x;          // H/64 = 32
  const int mt32 = blockIdx.y;          // T/32 = 256
  const int t    = threadIdx.x;

  const int m_l  = t >> 3;              // 0..31
  const int k4a  = t & 7;               // 0..7
  const float* row = x + (size_t)(mt32 * 32 + m_l) * HIDDEN + kb0 * 64;
#pragma unroll
  for (int h = 0; h < 2; ++h) {
    const int k4 = k4a + h * 8;         // 0..15
    const float4 f = *(const float4*)(row + k4 * 4);
    lt[(k4 * 4 + 0) * 33 + m_l] = f.x;
    lt[(k4 * 4 + 1) * 33 + m_l] = f.y;
    lt[(k4 * 4 + 2) * 33 + m_l] = f.z;
    lt[(k4 * 4 + 3) * 33 + m_l] = f.w;
  }
  __syncthreads();

  const int kb_l = t >> 5;              // 0..7
  const int m_o  = t & 31;              // 0..31
  const int P[8] = {0, 4, 1, 5, 2, 6, 3, 7};
  f16x8 v;
#pragma unroll
  for (int j = 0; j < 8; ++j)
    v[j] = (_Float16)lt[(kb_l * 8 + P[j]) * 33 + m_o];
  const int kb   = kb0 * 8 + kb_l;      // 0..255
  const int mt128 = mt32 >> 2;
  const int m128  = (mt32 & 3) * 32 + m_o;
  *(f16x8*)(xs + ((size_t)(mt128 * 256 + kb) * 128 + m128) * 8) = v;
}

// GPTQ dequant (down weights only): qweight [K/8,N] int32 -> staged [K/8][N][8] f16
__global__ void k_dequant(const unsigned int* __restrict__ qw,
                          const unsigned int* __restrict__ qz,
                          const float* __restrict__ sc,
                          _Float16* __restrict__ out, int N, int N8) {
  const int n  = blockIdx.x * 256 + threadIdx.x;
  const int k8 = blockIdx.y;
  const int g  = k8 >> 4;
  unsigned int q  = qw[(size_t)k8 * N + n];
  unsigned int zw = qz[(size_t)g * N8 + (n >> 3)];
  int   z1 = (int)((zw >> ((n & 7) * 4)) & 0xFu) + 1;
  float s  = sc[(size_t)g * N + n];
  f16x8 w;
#pragma unroll
  for (int j = 0; j < 8; ++j)
    w[j] = (_Float16)((float)((int)((q >> (4 * j)) & 0xFu) - z1) * s);
  *(f16x8*)(out + ((size_t)k8 * N + n) * 8) = w;
}

// ---------------- GEMM1: fused int4 dequant, 2 blocks/CU TLP, 128x128 dual-B ------------
// block: 256 thr = 4 waves (2x2), tile 128x128, BK=64, MFMA 16x16x32 f16.
// A: staged f16 via global_load_lds (16KB/tile). B: NO LDS -- each lane's B-fragment
// (8 consecutive K at one col) is exactly ONE packed qweight u32; loaded global->reg
// (L1 dedups the wm-pair), dequanted in-reg via dq8. Scales/zeros reloaded per
// 128-K group (every 2 iters). Supply per block: A 0.5MB + B-packed 0.26MB.
__global__ __launch_bounds__(256, 2)
void k_gemm_gateup(const _Float16* __restrict__ xs,
                   const unsigned int* __restrict__ gq,
                   const unsigned int* __restrict__ gz,
                   const float* __restrict__ gs,
                   const unsigned int* __restrict__ uq,
                   const unsigned int* __restrict__ uz,
                   const float* __restrict__ us,
                   _Float16* __restrict__ hs) {
  __shared__ _Float16 Al[8192];         // [8 kb][128][8] = 16KB
  const int nt = blockIdx.x, mt = blockIdx.y;
  const int tid = threadIdx.x;
  const int wave = tid >> 6, lane = tid & 63;
  const int wm = wave >> 1, wn = wave & 1;
  const int row16 = lane >> 4, col = lane & 15;
  const int slot = wave * 4;

  const _Float16* gA = xs + (size_t)mt * 256 * 1024;   // + kit*8192 per iter

  int afo[4], ncol[4];
#pragma unroll
  for (int i = 0; i < 4; ++i) {
    afo[i]  = (row16 * 128 + wm * 64 + i * 16 + col) * 8;
    ncol[i] = nt * 128 + wn * 64 + i * 16 + col;       // global INTER col
  }

  const f32x4 zero = {0.f, 0.f, 0.f, 0.f};
  f32x4 accg[4][4], accu[4][4];
#pragma unroll
  for (int i = 0; i < 4; ++i)
#pragma unroll
    for (int j = 0; j < 4; ++j) { accg[i][j] = zero; accu[i][j] = zero; }

  f16x2 sg2[4], cg2[4], su2[4], cu2[4];

  for (int kit = 0; kit < HIDDEN / 64; ++kit) {        // 32 iters
    // per-group scale/zero reload (group = 128 K-rows = 2 iters)
    if ((kit & 1) == 0) {
      const int g = kit >> 1;
#pragma unroll
      for (int ni = 0; ni < 4; ++ni) {
        const int n = ncol[ni];
        const float        sgf = gs[(size_t)g * INTER + n];
        const float        suf = us[(size_t)g * INTER + n];
        const unsigned int zgw = gz[(size_t)g * (INTER / 8) + (n >> 3)];
        const unsigned int zuw = uz[(size_t)g * (INTER / 8) + (n >> 3)];
        const int z1g = (int)((zgw >> ((n & 7) * 4)) & 0xFu) + 1;
        const int z1u = (int)((zuw >> ((n & 7) * 4)) & 0xFu) + 1;
        const _Float16 shg = (_Float16)sgf, shu = (_Float16)suf;
        const _Float16 chg = (_Float16)(float)(1024 + z1g);
        const _Float16 chu = (_Float16)(float)(1024 + z1u);
        sg2[ni] = (f16x2){shg, shg}; cg2[ni] = (f16x2){chg, chg};
        su2[ni] = (f16x2){shu, shu}; cu2[ni] = (f16x2){chu, chu};
      }
    }

    // B packed loads: one u32 per fragment, issued early (overlap barrier wait)
    unsigned int bqg[2][4], bqu[2][4];
#pragma unroll
    for (int ks = 0; ks < 2; ++ks) {
      const size_t ro = (size_t)((kit * 8 + ks * 4 + row16)) * INTER;
#pragma unroll
      for (int ni = 0; ni < 4; ++ni) {
        bqg[ks][ni] = gq[ro + ncol[ni]];
        bqu[ks][ni] = uq[ro + ncol[ni]];
      }
    }

    __syncthreads();                                    // protect A LDS reuse
#pragma unroll
    for (int q = 0; q < 4; ++q) {
      const int c = (slot + q) * 64 + lane;             // 16B chunk id in A tile
      async_copy16(gA + (size_t)kit * 8192 + (size_t)c * 8,
                   (char*)Al + (size_t)(slot + q) * 1024);
    }
    __syncthreads();                                    // drains vmcnt(0) (A + B regs)

#pragma unroll
    for (int ks = 0; ks < 2; ++ks) {
      const int kadd = ks * 4096;                       // +4 kb rows
      f16x8 af[4], bg[4], bu[4];
#pragma unroll
      for (int i = 0; i < 4; ++i)
        af[i] = *(const f16x8*)(Al + kadd + afo[i]);
#pragma unroll
      for (int ni = 0; ni < 4; ++ni) {
        bg[ni] = dq8(bqg[ks][ni], sg2[ni], cg2[ni]);
        bu[ni] = dq8(bqu[ks][ni], su2[ni], cu2[ni]);
      }
#pragma unroll
      for (int mi = 0; mi < 4; ++mi)
#pragma unroll
        for (int ni = 0; ni < 4; ++ni) {
          accg[mi][ni] = __builtin_amdgcn_mfma_f32_16x16x32_f16(af[mi], bg[ni], accg[mi][ni], 0, 0, 0);
          accu[mi][ni] = __builtin_amdgcn_mfma_f32_16x16x32_f16(af[mi], bu[ni], accu[mi][ni], 0, 0, 0);
        }
    }
  }
  // epilogue: h = g*sigmoid(g)*u, scatter into staged layout (2B stores, natural k-order)
#pragma unroll
  for (int mi = 0; mi < 4; ++mi)
#pragma unroll
    for (int ni = 0; ni < 4; ++ni) {
      const int kg = ncol[ni];
      const size_t base = (size_t)(mt * (INTER / 8) + (kg >> 3)) * 1024 + (kg & 7);
#pragma unroll
      for (int r = 0; r < 4; ++r) {
        float g = accg[mi][ni][r], u = accu[mi][ni][r];
        float h = g / (1.f + __expf(-g)) * u;
        const int ml = wm * 64 + mi * 16 + row16 * 4 + r;
        hs[base + (size_t)ml * 8] = (_Float16)h;
      }
    }
}

// ---------------- GEMM2: 8-phase counted-vmcnt, tile 256x256 (proven, unchanged) ----------------
__global__ __launch_bounds__(512, 1)
void k_gemm_down(const _Float16* __restrict__ hs,
                 const _Float16* __restrict__ wd,
                 float* __restrict__ out) {
  extern __shared__ _Float16 lds[];
  _Float16* A0 = lds;            // [2 half][8 kb][128][8] = 16384 f16
  _Float16* A1 = lds + 16384;
  _Float16* B0 = lds + 32768;    // [8 kb][256][8] = 16384 f16
  _Float16* B1 = lds + 49152;

  const int bid  = blockIdx.x;                   // 256 = 8*32, %8==0
  const int wgid = (bid & 7) * 32 + (bid >> 3);  // XCD-chunked swizzle
  const int nt = wgid >> 5, mt = wgid & 31;      // each XCD owns one B-panel (L2-fit)

  const int tid  = threadIdx.x;
  const int wave = tid >> 6, lane = tid & 63;
  const int wm = wave >> 2, wn = wave & 3;       // 2M x 4N
  const int row16 = lane >> 4, col = lane & 15;

  int afo[8], bfo[4];
#pragma unroll
  for (int i = 0; i < 8; ++i)
    afo[i] = wm * 8192 + row16 * 1024 + (i * 16 + col) * 8;
#pragma unroll
  for (int i = 0; i < 4; ++i)
    bfo[i] = row16 * 2048 + (wn * 64 + i * 16 + col) * 8;

  const f32x4 zero = {0.f, 0.f, 0.f, 0.f};
  f32x4 acc[8][4];
#pragma unroll
  for (int i = 0; i < 8; ++i)
#pragma unroll
    for (int j = 0; j < 4; ++j) acc[i][j] = zero;

  f16x8 af[4][2], bf[4][2];

#define DN_LOAD_A(AP, mh) \
  _Pragma("unroll") for (int mi_ = 0; mi_ < 4; ++mi_) \
  _Pragma("unroll") for (int ks_ = 0; ks_ < 2; ++ks_) \
    af[mi_][ks_] = *(const f16x8*)((AP) + afo[(mh) * 4 + mi_] + ks_ * 4096);

#define DN_LOAD_B(BP, nh) \
  _Pragma("unroll") for (int ni_ = 0; ni_ < 2; ++ni_) \
  _Pragma("unroll") for (int ks_ = 0; ks_ < 2; ++ks_) \
    bf[(nh) * 2 + ni_][ks_] = *(const f16x8*)((BP) + bfo[(nh) * 2 + ni_] + ks_ * 8192);

#define DN_MFMA(mh, nh) \
  _Pragma("unroll") for (int mi_ = 0; mi_ < 4; ++mi_) \
  _Pragma("unroll") for (int ni_ = 0; ni_ < 2; ++ni_) \
  _Pragma("unroll") for (int ks_ = 0; ks_ < 2; ++ks_) \
    acc[(mh) * 4 + mi_][(nh) * 2 + ni_] = __builtin_amdgcn_mfma_f32_16x16x32_f16( \
        af[mi_][ks_], bf[(nh) * 2 + ni_][ks_], acc[(mh) * 4 + mi_][(nh) * 2 + ni_], 0, 0, 0);

#define DN_STAGE_A(AP, kt) do { const int kt_ = (kt); \
  _Pragma("unroll") for (int q_ = 0; q_ < 4; ++q_) { \
    const int i_ = q_ * 512 + tid; \
    async_copy16(hs + (size_t)(((2 * mt + (i_ >> 10)) * 704 + kt_ * 8 + ((i_ >> 7) & 7)) * 128 + (i_ & 127)) * 8, \
                 (char*)(AP) + q_ * 8192 + wave * 1024); } } while (0)

#define DN_STAGE_B(BP, kt) do { const int kt_ = (kt); \
  _Pragma("unroll") for (int q_ = 0; q_ < 4; ++q_) { \
    const int i_ = q_ * 512 + tid; \
    async_copy16(wd + (size_t)((kt_ * 8 + (i_ >> 8)) * HIDDEN + nt * 256 + (i_ & 255)) * 8, \
                 (char*)(BP) + q_ * 8192 + wave * 1024); } } while (0)

  // prologue: tile0 -> buf0 (8 loads), tile1 -> buf1 (8 loads)
  DN_STAGE_B(B0, 0); DN_STAGE_A(A0, 0);
  DN_STAGE_B(B1, 1); DN_STAGE_A(A1, 1);
  WAITVM(8);          // tile0 complete; tile1's 8 stay in flight
  BAR; SB0;

  for (int t2 = 0; t2 < 44; ++t2) {
    const int e2 = (2 * t2 + 2 < 88) ? 2 * t2 + 2 : 87;
    const int o2 = (2 * t2 + 3 < 88) ? 2 * t2 + 3 : 87;
    // ph1: E Q(0,0)
    DN_LOAD_A(A0, 0); DN_LOAD_B(B0, 0);
    BAR; LGKM0; PRIO(1); DN_MFMA(0, 0); PRIO(0); BAR; SB0;
    // ph2: E Q(0,1)
    DN_LOAD_B(B0, 1);
    BAR; LGKM0; PRIO(1); DN_MFMA(0, 1); PRIO(0); BAR; SB0;
    // ph3: E Q(1,0)
    DN_LOAD_A(A0, 1); DN_STAGE_B(B0, e2);
    BAR; LGKM0; PRIO(1); DN_MFMA(1, 0); PRIO(0); BAR; SB0;
    // ph4: E Q(1,1) + counted wait (tile O resident)
    DN_STAGE_A(A0, e2);
    BAR; LGKM0; PRIO(1); DN_MFMA(1, 1); PRIO(0); WAITVM(8); BAR; SB0;
    // ph5: O Q(0,0)
    DN_LOAD_A(A1, 0); DN_LOAD_B(B1, 0);
    BAR; LGKM0; PRIO(1); DN_MFMA(0, 0); PRIO(0); BAR; SB0;
    // ph6: O Q(0,1)
    DN_LOAD_B(B1, 1);
    BAR; LGKM0; PRIO(1); DN_MFMA(0, 1); PRIO(0); BAR; SB0;
    // ph7: O Q(1,0)
    DN_LOAD_A(A1, 1); DN_STAGE_B(B1, o2);
    BAR; LGKM0; PRIO(1); DN_MFMA(1, 0); PRIO(0); BAR; SB0;
    // ph8: O Q(1,1) + counted wait (tile E+2 resident)
    DN_STAGE_A(A1, o2);
    BAR; LGKM0; PRIO(1); DN_MFMA(1, 1); PRIO(0); WAITVM(8); BAR; SB0;
  }
  WAITVM(0);

#pragma unroll
  for (int mi = 0; mi < 8; ++mi)
#pragma unroll
    for (int ni = 0; ni < 4; ++ni) {
      const int n = nt * 256 + wn * 64 + ni * 16 + col;
#pragma unroll
      for (int r = 0; r < 4; ++r) {
        const int m = mt * 256 + wm * 128 + mi * 16 + row16 * 4 + r;
        out[(size_t)m * HIDDEN + n] = acc[mi][ni][r];
      }
    }
#undef DN_LOAD_A
#undef DN_LOAD_B
#undef DN_MFMA
#undef DN_STAGE_A
#undef DN_STAGE_B
}

extern "C" void kernel_launch(void* const* d_in, const int* in_sizes, int n_in,
                              void* d_out, int out_size, void* d_ws, size_t ws_size,
                              hipStream_t stream) {
  (void)in_sizes; (void)n_in; (void)out_size; (void)ws_size;
  const float*        x  = (const float*)d_in[0];
  const unsigned int* gq = (const unsigned int*)d_in[1];
  const unsigned int* gz = (const unsigned int*)d_in[2];
  const float*        gs = (const float*)d_in[3];
  const unsigned int* uq = (const unsigned int*)d_in[4];
  const unsigned int* uz = (const unsigned int*)d_in[5];
  const float*        us = (const float*)d_in[6];
  const unsigned int* dq = (const unsigned int*)d_in[7];
  const unsigned int* dz = (const unsigned int*)d_in[8];
  const float*        ds = (const float*)d_in[9];
  float* out = (float*)d_out;

  // workspace layout (bytes):
  // xs  [0, 32MB)      x staged f16 (k-permuted within 8-groups)
  // wdd [32MB, +23MB)  dequanted down weights, staged f16
  // hs  [+55MB)        h staged f16   -> total ~147MB
  char* ws = (char*)d_ws;
  _Float16* xs  = (_Float16*)ws;
  _Float16* wdd = (_Float16*)(ws + (size_t)TOKENS * HIDDEN * 2);
  _Float16* hs  = wdd + (size_t)INTER * HIDDEN;

  static bool attr_set = false;
  if (!attr_set) {
    hipFuncSetAttribute((const void*)k_gemm_down,
                        hipFuncAttributeMaxDynamicSharedMemorySize, 131072);
    attr_set = true;
  }

  k_convert_x<<<dim3(HIDDEN / 64, TOKENS / 32), 256, 0, stream>>>(x, xs);
  k_dequant<<<dim3(HIDDEN / 256, INTER / 8), 256, 0, stream>>>(dq, dz, ds, wdd, HIDDEN, HIDDEN / 8);
  k_gemm_gateup<<<dim3(INTER / 128, TOKENS / 128), 256, 0, stream>>>(
      xs, gq, gz, gs, uq, uz, us, hs);
  k_gemm_down<<<dim3(256), 512, 131072, stream>>>(hs, wdd, out);
}

// Round 5
// 670.908 us; speedup vs baseline: 1.1353x; 1.1353x over previous
//
#include <hip/hip_runtime.h>

#define TOKENS 8192
#define HIDDEN 2048
#define INTER  5632

typedef _Float16 f16x8 __attribute__((ext_vector_type(8)));
typedef _Float16 f16x4 __attribute__((ext_vector_type(4)));
typedef _Float16 f16x2 __attribute__((ext_vector_type(2)));
typedef float    f32x4 __attribute__((ext_vector_type(4)));

// async global->LDS, 16B per lane. LDS dest = wave-uniform base + lane*16.
__device__ __forceinline__ void async_copy16(const void* g, void* l) {
  __builtin_amdgcn_global_load_lds(
      (const __attribute__((address_space(1))) unsigned int*)g,
      (__attribute__((address_space(3))) unsigned int*)l, 16, 0, 0);
}

#define BAR   __builtin_amdgcn_s_barrier()
#define SB0   __builtin_amdgcn_sched_barrier(0)
#define LGKM0 do { asm volatile("s_waitcnt lgkmcnt(0)" ::: "memory"); SB0; } while (0)
#define WAITVM(n) asm volatile("s_waitcnt vmcnt(" #n ")" ::: "memory")
#define PRIO(x) __builtin_amdgcn_s_setprio(x)

// GPTQ int4 -> f16x8 dequant, magic-bias form (exact: (h-c) integer-exact in f16,
// single rounding on *s). ((q>>s)&M)|BIAS shaped for v_and_or_b32 fusion.
// Output k-order [0,4,1,5,2,6,3,7]; A staged with the same permutation.
__device__ __forceinline__ f16x8 dq8(unsigned int q, f16x2 s2, f16x2 c2) {
  union { unsigned int u[4]; f16x8 v; } r;
#pragma unroll
  for (int j = 0; j < 4; ++j) {
    const unsigned int qs = q >> (4 * j);
    const unsigned int t  = (qs & 0x000F000Fu) | 0x64006400u;   // and_or
    f16x2 h = __builtin_bit_cast(f16x2, t);
    h = (h - c2) * s2;
    r.u[j] = __builtin_bit_cast(unsigned int, h);
  }
  return r.v;
}

// ---------------- producers ----------------

// x [T,H] fp32 -> staged [T/128][H/8][128][8] f16, k-order permuted [0,4,1,5,2,6,3,7]
// within each 8-group to match dq8's output order.
__global__ __launch_bounds__(256)
void k_convert_x(const float* __restrict__ x, _Float16* __restrict__ xs) {
  __shared__ float lt[64 * 33];
  const int kb0  = blockIdx.x;          // H/64 = 32
  const int mt32 = blockIdx.y;          // T/32 = 256
  const int t    = threadIdx.x;

  const int m_l  = t >> 3;              // 0..31
  const int k4a  = t & 7;               // 0..7
  const float* row = x + (size_t)(mt32 * 32 + m_l) * HIDDEN + kb0 * 64;
#pragma unroll
  for (int h = 0; h < 2; ++h) {
    const int k4 = k4a + h * 8;         // 0..15
    const float4 f = *(const float4*)(row + k4 * 4);
    lt[(k4 * 4 + 0) * 33 + m_l] = f.x;
    lt[(k4 * 4 + 1) * 33 + m_l] = f.y;
    lt[(k4 * 4 + 2) * 33 + m_l] = f.z;
    lt[(k4 * 4 + 3) * 33 + m_l] = f.w;
  }
  __syncthreads();

  const int kb_l = t >> 5;              // 0..7
  const int m_o  = t & 31;              // 0..31
  const int P[8] = {0, 4, 1, 5, 2, 6, 3, 7};
  f16x8 v;
#pragma unroll
  for (int j = 0; j < 8; ++j)
    v[j] = (_Float16)lt[(kb_l * 8 + P[j]) * 33 + m_o];
  const int kb   = kb0 * 8 + kb_l;      // 0..255
  const int mt128 = mt32 >> 2;
  const int m128  = (mt32 & 3) * 32 + m_o;
  *(f16x8*)(xs + ((size_t)(mt128 * 256 + kb) * 128 + m128) * 8) = v;
}

// GPTQ dequant (down weights only): qweight [K/8,N] int32 -> staged [K/8][N][8] f16
__global__ void k_dequant(const unsigned int* __restrict__ qw,
                          const unsigned int* __restrict__ qz,
                          const float* __restrict__ sc,
                          _Float16* __restrict__ out, int N, int N8) {
  const int n  = blockIdx.x * 256 + threadIdx.x;
  const int k8 = blockIdx.y;
  const int g  = k8 >> 4;
  unsigned int q  = qw[(size_t)k8 * N + n];
  unsigned int zw = qz[(size_t)g * N8 + (n >> 3)];
  int   z1 = (int)((zw >> ((n & 7) * 4)) & 0xFu) + 1;
  float s  = sc[(size_t)g * N + n];
  f16x8 w;
#pragma unroll
  for (int j = 0; j < 8; ++j)
    w[j] = (_Float16)((float)((int)((q >> (4 * j)) & 0xFu) - z1) * s);
  *(f16x8*)(out + ((size_t)k8 * N + n) * 8) = w;
}

// ---------------- GEMM1: fused dequant, wave-specialized (redundancy 1) ------------------
// 512 thr = 8 waves. Waves 0-3: gate; waves 4-7: up. Each wave: full 128 M-rows x
// one 32-col slice (acc 8x2 f32x4). Every B element dequanted by exactly ONE lane.
// BK=128 (= one GPTQ group per iter): A tile [16 kb][128][8] = 32KB LDS, 16 iters.
// B: packed u32 per fragment, global->reg, dq8 in-reg. 2 blocks/CU TLP.
// Epilogue: up-waves push u (f16) through LDS; gate-waves combine silu(g)*u -> hs.
__global__ __launch_bounds__(512, 4)
void k_gemm_gateup(const _Float16* __restrict__ xs,
                   const unsigned int* __restrict__ gq,
                   const unsigned int* __restrict__ gz,
                   const float* __restrict__ gs,
                   const unsigned int* __restrict__ uq,
                   const unsigned int* __restrict__ uz,
                   const float* __restrict__ us,
                   _Float16* __restrict__ hs) {
  __shared__ _Float16 smem[16384];      // 32KB: A [16 kb][128][8]; epilogue reuses
  const int nt = blockIdx.x, mt = blockIdx.y;
  const int tid  = threadIdx.x;
  const int wave = tid >> 6, lane = tid & 63;
  const int isUp = wave >> 2;           // 0 = gate, 1 = up
  const int wg4  = wave & 3;            // 32-col group within the 128-col tile
  const int row16 = lane >> 4, col = lane & 15;

  const unsigned int* bq = isUp ? uq : gq;
  const unsigned int* bz = isUp ? uz : gz;
  const float*        bs = isUp ? us : gs;

  int ncol[2];
  ncol[0] = nt * 128 + wg4 * 32 + col;
  ncol[1] = ncol[0] + 16;

  int afo[8];
#pragma unroll
  for (int i = 0; i < 8; ++i)
    afo[i] = (row16 * 128 + i * 16 + col) * 8;     // + ks*4096 per k-substep

  const _Float16* gA = xs + (size_t)mt * 256 * 1024;  // + kit*16384 per iter

  const f32x4 zero = {0.f, 0.f, 0.f, 0.f};
  f32x4 acc[8][2];
#pragma unroll
  for (int i = 0; i < 8; ++i) { acc[i][0] = zero; acc[i][1] = zero; }

  for (int kit = 0; kit < 16; ++kit) {             // 16 iters, 128 K each
    // group scales/zeros (group == kit)
    f16x2 s2[2], c2[2];
#pragma unroll
    for (int ni = 0; ni < 2; ++ni) {
      const int n = ncol[ni];
      const float        sf = bs[(size_t)kit * INTER + n];
      const unsigned int zw = bz[(size_t)kit * (INTER / 8) + (n >> 3)];
      const int z1 = (int)((zw >> ((n & 7) * 4)) & 0xFu) + 1;
      const _Float16 sh = (_Float16)sf;
      const _Float16 ch = (_Float16)(float)(1024 + z1);
      s2[ni] = (f16x2){sh, sh};
      c2[ni] = (f16x2){ch, ch};
    }

    // packed B loads: one u32 per fragment (8 per iter), issued before the barriers
    unsigned int bqr[4][2];
#pragma unroll
    for (int ks = 0; ks < 4; ++ks) {
      const size_t ro = (size_t)(kit * 16 + ks * 4 + row16) * INTER;
      bqr[ks][0] = bq[ro + ncol[0]];
      bqr[ks][1] = bq[ro + ncol[1]];
    }

    __syncthreads();                               // protect A LDS reuse
#pragma unroll
    for (int q = 0; q < 4; ++q) {
      const int c = q * 512 + tid;                 // 2048 x 16B chunks
      async_copy16(gA + (size_t)kit * 16384 + (size_t)c * 8, (char*)smem + (size_t)c * 16);
    }
    __syncthreads();                               // drains vmcnt(0) (A + B regs)

#pragma unroll
    for (int ks = 0; ks < 4; ++ks) {
      f16x8 bf[2];
      bf[0] = dq8(bqr[ks][0], s2[0], c2[0]);
      bf[1] = dq8(bqr[ks][1], s2[1], c2[1]);
#pragma unroll
      for (int mh = 0; mh < 2; ++mh) {
        f16x8 af[4];
#pragma unroll
        for (int i = 0; i < 4; ++i)
          af[i] = *(const f16x8*)(smem + ks * 4096 + afo[mh * 4 + i]);
#pragma unroll
        for (int mi = 0; mi < 4; ++mi)
#pragma unroll
          for (int ni = 0; ni < 2; ++ni)
            acc[mh * 4 + mi][ni] = __builtin_amdgcn_mfma_f32_16x16x32_f16(
                af[mi], bf[ni], acc[mh * 4 + mi][ni], 0, 0, 0);
      }
    }
  }

  // epilogue: exchange u via LDS (f16), gate waves combine and store
  __syncthreads();
  if (isUp) {
    // layout: [wg4][frag 16][lane 64] x f16x4 (8B) = 32KB
    _Float16* epi = smem;
#pragma unroll
    for (int mi = 0; mi < 8; ++mi)
#pragma unroll
      for (int ni = 0; ni < 2; ++ni) {
        f16x4 u4;
#pragma unroll
        for (int r = 0; r < 4; ++r) u4[r] = (_Float16)acc[mi][ni][r];
        *(f16x4*)(epi + (((size_t)wg4 * 16 + mi * 2 + ni) * 64 + lane) * 4) = u4;
      }
  }
  __syncthreads();
  if (!isUp) {
    const _Float16* epi = smem;
#pragma unroll
    for (int mi = 0; mi < 8; ++mi)
#pragma unroll
      for (int ni = 0; ni < 2; ++ni) {
        const f16x4 u4 = *(const f16x4*)(epi + (((size_t)wg4 * 16 + mi * 2 + ni) * 64 + lane) * 4);
        const int kg = ncol[ni];
        const size_t base = (size_t)(mt * (INTER / 8) + (kg >> 3)) * 1024 + (kg & 7);
#pragma unroll
        for (int r = 0; r < 4; ++r) {
          const float g = acc[mi][ni][r];
          const float u = (float)u4[r];
          const float h = g / (1.f + __expf(-g)) * u;
          const int ml = mi * 16 + row16 * 4 + r;
          hs[base + (size_t)ml * 8] = (_Float16)h;
        }
      }
  }
}

// ---------------- GEMM2: 8-phase counted-vmcnt, tile 256x256 (proven, unchanged) ----------------
__global__ __launch_bounds__(512, 1)
void k_gemm_down(const _Float16* __restrict__ hs,
                 const _Float16* __restrict__ wd,
                 float* __restrict__ out) {
  extern __shared__ _Float16 lds[];
  _Float16* A0 = lds;            // [2 half][8 kb][128][8] = 16384 f16
  _Float16* A1 = lds + 16384;
  _Float16* B0 = lds + 32768;    // [8 kb][256][8] = 16384 f16
  _Float16* B1 = lds + 49152;

  const int bid  = blockIdx.x;                   // 256 = 8*32, %8==0
  const int wgid = (bid & 7) * 32 + (bid >> 3);  // XCD-chunked swizzle
  const int nt = wgid >> 5, mt = wgid & 31;      // each XCD owns one B-panel (L2-fit)

  const int tid  = threadIdx.x;
  const int wave = tid >> 6, lane = tid & 63;
  const int wm = wave >> 2, wn = wave & 3;       // 2M x 4N
  const int row16 = lane >> 4, col = lane & 15;

  int afo[8], bfo[4];
#pragma unroll
  for (int i = 0; i < 8; ++i)
    afo[i] = wm * 8192 + row16 * 1024 + (i * 16 + col) * 8;
#pragma unroll
  for (int i = 0; i < 4; ++i)
    bfo[i] = row16 * 2048 + (wn * 64 + i * 16 + col) * 8;

  const f32x4 zero = {0.f, 0.f, 0.f, 0.f};
  f32x4 acc[8][4];
#pragma unroll
  for (int i = 0; i < 8; ++i)
#pragma unroll
    for (int j = 0; j < 4; ++j) acc[i][j] = zero;

  f16x8 af[4][2], bf[4][2];

#define DN_LOAD_A(AP, mh) \
  _Pragma("unroll") for (int mi_ = 0; mi_ < 4; ++mi_) \
  _Pragma("unroll") for (int ks_ = 0; ks_ < 2; ++ks_) \
    af[mi_][ks_] = *(const f16x8*)((AP) + afo[(mh) * 4 + mi_] + ks_ * 4096);

#define DN_LOAD_B(BP, nh) \
  _Pragma("unroll") for (int ni_ = 0; ni_ < 2; ++ni_) \
  _Pragma("unroll") for (int ks_ = 0; ks_ < 2; ++ks_) \
    bf[(nh) * 2 + ni_][ks_] = *(const f16x8*)((BP) + bfo[(nh) * 2 + ni_] + ks_ * 8192);

#define DN_MFMA(mh, nh) \
  _Pragma("unroll") for (int mi_ = 0; mi_ < 4; ++mi_) \
  _Pragma("unroll") for (int ni_ = 0; ni_ < 2; ++ni_) \
  _Pragma("unroll") for (int ks_ = 0; ks_ < 2; ++ks_) \
    acc[(mh) * 4 + mi_][(nh) * 2 + ni_] = __builtin_amdgcn_mfma_f32_16x16x32_f16( \
        af[mi_][ks_], bf[(nh) * 2 + ni_][ks_], acc[(mh) * 4 + mi_][(nh) * 2 + ni_], 0, 0, 0);

#define DN_STAGE_A(AP, kt) do { const int kt_ = (kt); \
  _Pragma("unroll") for (int q_ = 0; q_ < 4; ++q_) { \
    const int i_ = q_ * 512 + tid; \
    async_copy16(hs + (size_t)(((2 * mt + (i_ >> 10)) * 704 + kt_ * 8 + ((i_ >> 7) & 7)) * 128 + (i_ & 127)) * 8, \
                 (char*)(AP) + q_ * 8192 + wave * 1024); } } while (0)

#define DN_STAGE_B(BP, kt) do { const int kt_ = (kt); \
  _Pragma("unroll") for (int q_ = 0; q_ < 4; ++q_) { \
    const int i_ = q_ * 512 + tid; \
    async_copy16(wd + (size_t)((kt_ * 8 + (i_ >> 8)) * HIDDEN + nt * 256 + (i_ & 255)) * 8, \
                 (char*)(BP) + q_ * 8192 + wave * 1024); } } while (0)

  // prologue: tile0 -> buf0 (8 loads), tile1 -> buf1 (8 loads)
  DN_STAGE_B(B0, 0); DN_STAGE_A(A0, 0);
  DN_STAGE_B(B1, 1); DN_STAGE_A(A1, 1);
  WAITVM(8);          // tile0 complete; tile1's 8 stay in flight
  BAR; SB0;

  for (int t2 = 0; t2 < 44; ++t2) {
    const int e2 = (2 * t2 + 2 < 88) ? 2 * t2 + 2 : 87;
    const int o2 = (2 * t2 + 3 < 88) ? 2 * t2 + 3 : 87;
    // ph1: E Q(0,0)
    DN_LOAD_A(A0, 0); DN_LOAD_B(B0, 0);
    BAR; LGKM0; PRIO(1); DN_MFMA(0, 0); PRIO(0); BAR; SB0;
    // ph2: E Q(0,1)
    DN_LOAD_B(B0, 1);
    BAR; LGKM0; PRIO(1); DN_MFMA(0, 1); PRIO(0); BAR; SB0;
    // ph3: E Q(1,0)
    DN_LOAD_A(A0, 1); DN_STAGE_B(B0, e2);
    BAR; LGKM0; PRIO(1); DN_MFMA(1, 0); PRIO(0); BAR; SB0;
    // ph4: E Q(1,1) + counted wait (tile O resident)
    DN_STAGE_A(A0, e2);
    BAR; LGKM0; PRIO(1); DN_MFMA(1, 1); PRIO(0); WAITVM(8); BAR; SB0;
    // ph5: O Q(0,0)
    DN_LOAD_A(A1, 0); DN_LOAD_B(B1, 0);
    BAR; LGKM0; PRIO(1); DN_MFMA(0, 0); PRIO(0); BAR; SB0;
    // ph6: O Q(0,1)
    DN_LOAD_B(B1, 1);
    BAR; LGKM0; PRIO(1); DN_MFMA(0, 1); PRIO(0); BAR; SB0;
    // ph7: O Q(1,0)
    DN_LOAD_A(A1, 1); DN_STAGE_B(B1, o2);
    BAR; LGKM0; PRIO(1); DN_MFMA(1, 0); PRIO(0); BAR; SB0;
    // ph8: O Q(1,1) + counted wait (tile E+2 resident)
    DN_STAGE_A(A1, o2);
    BAR; LGKM0; PRIO(1); DN_MFMA(1, 1); PRIO(0); WAITVM(8); BAR; SB0;
  }
  WAITVM(0);

#pragma unroll
  for (int mi = 0; mi < 8; ++mi)
#pragma unroll
    for (int ni = 0; ni < 4; ++ni) {
      const int n = nt * 256 + wn * 64 + ni * 16 + col;
#pragma unroll
      for (int r = 0; r < 4; ++r) {
        const int m = mt * 256 + wm * 128 + mi * 16 + row16 * 4 + r;
        out[(size_t)m * HIDDEN + n] = acc[mi][ni][r];
      }
    }
#undef DN_LOAD_A
#undef DN_LOAD_B
#undef DN_MFMA
#undef DN_STAGE_A
#undef DN_STAGE_B
}

extern "C" void kernel_launch(void* const* d_in, const int* in_sizes, int n_in,
                              void* d_out, int out_size, void* d_ws, size_t ws_size,
                              hipStream_t stream) {
  (void)in_sizes; (void)n_in; (void)out_size; (void)ws_size;
  const float*        x  = (const float*)d_in[0];
  const unsigned int* gq = (const unsigned int*)d_in[1];
  const unsigned int* gz = (const unsigned int*)d_in[2];
  const float*        gs = (const float*)d_in[3];
  const unsigned int* uq = (const unsigned int*)d_in[4];
  const unsigned int* uz = (const unsigned int*)d_in[5];
  const float*        us = (const float*)d_in[6];
  const unsigned int* dq = (const unsigned int*)d_in[7];
  const unsigned int* dz = (const unsigned int*)d_in[8];
  const float*        ds = (const float*)d_in[9];
  float* out = (float*)d_out;

  // workspace layout (bytes):
  // xs  [0, 32MB)      x staged f16 (k-permuted within 8-groups)
  // wdd [32MB, +23MB)  dequanted down weights, staged f16
  // hs  [+55MB)        h staged f16   -> total ~147MB
  char* ws = (char*)d_ws;
  _Float16* xs  = (_Float16*)ws;
  _Float16* wdd = (_Float16*)(ws + (size_t)TOKENS * HIDDEN * 2);
  _Float16* hs  = wdd + (size_t)INTER * HIDDEN;

  static bool attr_set = false;
  if (!attr_set) {
    hipFuncSetAttribute((const void*)k_gemm_down,
                        hipFuncAttributeMaxDynamicSharedMemorySize, 131072);
    attr_set = true;
  }

  k_convert_x<<<dim3(HIDDEN / 64, TOKENS / 32), 256, 0, stream>>>(x, xs);
  k_dequant<<<dim3(HIDDEN / 256, INTER / 8), 256, 0, stream>>>(dq, dz, ds, wdd, HIDDEN, HIDDEN / 8);
  k_gemm_gateup<<<dim3(INTER / 128, TOKENS / 128), 512, 0, stream>>>(
      xs, gq, gz, gs, uq, uz, us, hs);
  k_gemm_down<<<dim3(256), 512, 131072, stream>>>(hs, wdd, out);
}

// Round 6
// 630.242 us; speedup vs baseline: 1.2085x; 1.0645x over previous
//
#include <hip/hip_runtime.h>

#define TOKENS 8192
#define HIDDEN 2048
#define INTER  5632
#define NKIT   32      // HIDDEN / 64

typedef _Float16 f16x8 __attribute__((ext_vector_type(8)));
typedef _Float16 f16x2 __attribute__((ext_vector_type(2)));
typedef float    f32x4 __attribute__((ext_vector_type(4)));

// async global->LDS. LDS dest = wave-uniform base + lane*size.
__device__ __forceinline__ void async_copy16(const void* g, void* l) {
  __builtin_amdgcn_global_load_lds(
      (const __attribute__((address_space(1))) unsigned int*)g,
      (__attribute__((address_space(3))) unsigned int*)l, 16, 0, 0);
}
__device__ __forceinline__ void async_copy4(const void* g, void* l) {
  __builtin_amdgcn_global_load_lds(
      (const __attribute__((address_space(1))) unsigned int*)g,
      (__attribute__((address_space(3))) unsigned int*)l, 4, 0, 0);
}

#define BAR   __builtin_amdgcn_s_barrier()
#define SB0   __builtin_amdgcn_sched_barrier(0)
#define LGKM0 do { asm volatile("s_waitcnt lgkmcnt(0)" ::: "memory"); SB0; } while (0)
#define WAITVM(n) asm volatile("s_waitcnt vmcnt(" #n ")" ::: "memory")
#define PRIO(x) __builtin_amdgcn_s_setprio(x)

// GPTQ int4 -> f16x8, magic-bias form: (h - c)*s with h = 0x6400|nib pair.
// (h-c) is integer-exact in f16; single rounding on *s.
// Output k-order [0,4,1,5,2,6,3,7]; A is staged with the same permutation.
__device__ __forceinline__ f16x8 dq8(unsigned int q, f16x2 s2, f16x2 c2) {
  union { unsigned int u[4]; f16x8 v; } r;
#pragma unroll
  for (int j = 0; j < 4; ++j) {
    const unsigned int t = ((q >> (4 * j)) & 0x000F000Fu) | 0x64006400u;
    f16x2 h = __builtin_bit_cast(f16x2, t);
    h = (h - c2) * s2;
    r.u[j] = __builtin_bit_cast(unsigned int, h);
  }
  return r.v;
}

// ---------------- producers ----------------

// x [T,H] fp32 -> staged [T/128][H/8][128][8] f16, k-order permuted [0,4,1,5,2,6,3,7]
// within each 8-group to match dq8's output order.
__global__ __launch_bounds__(256)
void k_convert_x(const float* __restrict__ x, _Float16* __restrict__ xs) {
  __shared__ float lt[64 * 33];
  const int kb0  = blockIdx.x;          // H/64 = 32
  const int mt32 = blockIdx.y;          // T/32 = 256
  const int t    = threadIdx.x;

  const int m_l  = t >> 3;              // 0..31
  const int k4a  = t & 7;               // 0..7
  const float* row = x + (size_t)(mt32 * 32 + m_l) * HIDDEN + kb0 * 64;
#pragma unroll
  for (int h = 0; h < 2; ++h) {
    const int k4 = k4a + h * 8;         // 0..15
    const float4 f = *(const float4*)(row + k4 * 4);
    lt[(k4 * 4 + 0) * 33 + m_l] = f.x;
    lt[(k4 * 4 + 1) * 33 + m_l] = f.y;
    lt[(k4 * 4 + 2) * 33 + m_l] = f.z;
    lt[(k4 * 4 + 3) * 33 + m_l] = f.w;
  }
  __syncthreads();

  const int kb_l = t >> 5;              // 0..7
  const int m_o  = t & 31;              // 0..31
  const int P[8] = {0, 4, 1, 5, 2, 6, 3, 7};
  f16x8 v;
#pragma unroll
  for (int j = 0; j < 8; ++j)
    v[j] = (_Float16)lt[(kb_l * 8 + P[j]) * 33 + m_o];
  const int kb   = kb0 * 8 + kb_l;      // 0..255
  const int mt128 = mt32 >> 2;
  const int m128  = (mt32 & 3) * 32 + m_o;
  *(f16x8*)(xs + ((size_t)(mt128 * 256 + kb) * 128 + m128) * 8) = v;
}

// GPTQ dequant (down weights only): qweight [K/8,N] int32 -> staged [K/8][N][8] f16
__global__ void k_dequant(const unsigned int* __restrict__ qw,
                          const unsigned int* __restrict__ qz,
                          const float* __restrict__ sc,
                          _Float16* __restrict__ out, int N, int N8) {
  const int n  = blockIdx.x * 256 + threadIdx.x;
  const int k8 = blockIdx.y;
  const int g  = k8 >> 4;
  unsigned int q  = qw[(size_t)k8 * N + n];
  unsigned int zw = qz[(size_t)g * N8 + (n >> 3)];
  int   z1 = (int)((zw >> ((n & 7) * 4)) & 0xFu) + 1;
  float s  = sc[(size_t)g * N + n];
  f16x8 w;
#pragma unroll
  for (int j = 0; j < 8; ++j)
    w[j] = (_Float16)((float)((int)((q >> (4 * j)) & 0xFu) - z1) * s);
  *(f16x8*)(out + ((size_t)k8 * N + n) * 8) = w;
}

// ---------------- GEMM1: fused dequant, balanced-pipe geometry --------------------------
// 256 thr = 4 waves. Each wave: full 128 M x one 32-col slice x BOTH matrices.
//   acc = accg[8][2] + accu[8][2] (128 f32 -> AGPR); af reuse x4 (2 mats x 2 ni).
// Pipes per kit(K=64) per SIMD @2 blocks/CU: MFMA ~620cy, VALU ~660cy, LDS ~512cy.
// A: triple-buffered LDS (16KB x3), 2-deep prefetch, counted WAITVM(12), 1 barrier/kit.
// B: packed u32 global->reg (redundancy exactly 1 per block), dq8 in-reg.
// Scales/zeros: staged to LDS at prologue (never pollute the vmcnt ledger).
// vmcnt ledger (per wave, uniform): prologue scl4+zer2+B0(8)+A0(4)+B1(8)+A1(4)=30,
//   WAITVM(12) -> tile0+scl resident, tile1 (12) in flight.
//   kit k issues B(k+2) 8 + A(k+2) 4, ends WAITVM(12) -> drains tile k+1. Steady.
__global__ __launch_bounds__(256, 2)
void k_gemm_gateup(const _Float16* __restrict__ xs,
                   const unsigned int* __restrict__ gq,
                   const unsigned int* __restrict__ gz,
                   const float* __restrict__ gs,
                   const unsigned int* __restrict__ uq,
                   const unsigned int* __restrict__ uz,
                   const float* __restrict__ us,
                   _Float16* __restrict__ hs) {
  extern __shared__ _Float16 lds[];
  // A bufs: 3 x [8 kb][128][8] f16 = 16KB each at byte 0/16384/32768
  float*        scl = (float*)((char*)lds + 49152);        // [2][16][128] f32, 16KB
  unsigned int* zer = (unsigned int*)((char*)lds + 65536); // [2][16][16] u32, 2KB

  const int nt = blockIdx.x, mt = blockIdx.y;   // 44 x 64
  const int tid  = threadIdx.x;
  const int wave = tid >> 6, lane = tid & 63;
  const int wn = wave;                          // 32-col slice
  const int row16 = lane >> 4, col = lane & 15;

  const int ncol0 = nt * 128 + wn * 32 + col;   // ni=0; ni=1 -> +16
  const int boff  = row16 * INTER + ncol0;      // per-lane packed-B offset

  const f32x4 zero = {0.f, 0.f, 0.f, 0.f};
  f32x4 accg[8][2], accu[8][2];
#pragma unroll
  for (int i = 0; i < 8; ++i) {
    accg[i][0] = zero; accg[i][1] = zero;
    accu[i][0] = zero; accu[i][1] = zero;
  }

  unsigned int bqE[2][2][2], bqO[2][2][2];      // [mat][ni][ks], two kit banks
  f16x2 s2[2][2], c2[2][2];

#define GU_LOADB(BQ, KT) do { const int kt_ = (KT); \
  _Pragma("unroll") for (int ks_ = 0; ks_ < 2; ++ks_) { \
    const int ro_ = (kt_ * 8 + ks_ * 4) * INTER + boff; \
    BQ[0][0][ks_] = gq[ro_];      BQ[0][1][ks_] = gq[ro_ + 16]; \
    BQ[1][0][ks_] = uq[ro_];      BQ[1][1][ks_] = uq[ro_ + 16]; \
  } } while (0)

#define GU_STAGE_A(BUFB, KT) do { const int kt_ = (KT); const int bb_ = (BUFB); \
  _Pragma("unroll") for (int q_ = 0; q_ < 4; ++q_) { \
    const int i_ = q_ * 256 + tid; \
    async_copy16(xs + ((size_t)((mt * 256 + kt_ * 8 + (i_ >> 7)) * 128) + (i_ & 127)) * 8, \
                 (char*)lds + bb_ * 16384 + q_ * 4096 + wave * 1024); \
  } } while (0)

#define GU_BUILDSC(G) do { const int g_ = (G); \
  _Pragma("unroll") for (int mm_ = 0; mm_ < 2; ++mm_) \
  _Pragma("unroll") for (int ni_ = 0; ni_ < 2; ++ni_) { \
    const int cc_ = wn * 32 + ni_ * 16 + col; \
    const float sf_ = scl[(mm_ * 16 + g_) * 128 + cc_]; \
    const unsigned int zw_ = zer[(mm_ * 16 + g_) * 16 + (cc_ >> 3)]; \
    const int z1_ = (int)((zw_ >> ((cc_ & 7) * 4)) & 0xFu) + 1; \
    const _Float16 sh_ = (_Float16)sf_; \
    const _Float16 ch_ = (_Float16)(float)(1024 + z1_); \
    s2[mm_][ni_] = (f16x2){sh_, sh_}; c2[mm_][ni_] = (f16x2){ch_, ch_}; \
  } } while (0)

// one kit: dequant current bank -> prefetch k+2 into same bank -> compute -> counted wait
#define GU_KIT(K, BQ) do { \
  if (((K) & 1) == 0) GU_BUILDSC((K) >> 1); \
  f16x8 bf_[2][2][2]; \
  _Pragma("unroll") for (int mm_ = 0; mm_ < 2; ++mm_) \
  _Pragma("unroll") for (int ni_ = 0; ni_ < 2; ++ni_) \
  _Pragma("unroll") for (int ks_ = 0; ks_ < 2; ++ks_) \
    bf_[mm_][ni_][ks_] = dq8(BQ[mm_][ni_][ks_], s2[mm_][ni_], c2[mm_][ni_]); \
  const int kn_ = ((K) + 2 < NKIT) ? (K) + 2 : NKIT - 1; \
  GU_LOADB(BQ, kn_); \
  GU_STAGE_A(stg, kn_); \
  { const _Float16* ab_ = lds + cur * 8192; \
    _Pragma("unroll") for (int ks_ = 0; ks_ < 2; ++ks_) { \
      f16x8 af_[8]; \
      _Pragma("unroll") for (int mi_ = 0; mi_ < 8; ++mi_) \
        af_[mi_] = *(const f16x8*)(ab_ + ks_ * 4096 + (row16 * 128 + mi_ * 16 + col) * 8); \
      _Pragma("unroll") for (int mi_ = 0; mi_ < 8; ++mi_) \
      _Pragma("unroll") for (int ni_ = 0; ni_ < 2; ++ni_) { \
        accg[mi_][ni_] = __builtin_amdgcn_mfma_f32_16x16x32_f16(af_[mi_], bf_[0][ni_][ks_], accg[mi_][ni_], 0, 0, 0); \
        accu[mi_][ni_] = __builtin_amdgcn_mfma_f32_16x16x32_f16(af_[mi_], bf_[1][ni_][ks_], accu[mi_][ni_], 0, 0, 0); \
      } \
    } } \
  WAITVM(12); BAR; SB0; \
  cur = (cur == 2) ? 0 : cur + 1; \
  stg = (stg == 2) ? 0 : stg + 1; \
} while (0)

  // ---- prologue: scales+zeros -> LDS, tiles 0,1 -> bufs 0,1 + B banks ----
#pragma unroll
  for (int q = 0; q < 4; ++q) {                 // scales 16KB: 4x16B/thread
    const int c = q * 256 + tid;                // 0..1023
    const float* sp = (q >> 1) ? us : gs;       // mat = c>>9 = q>>1 (wave-uniform)
    const int g = (c >> 5) & 15;
    async_copy16(sp + (size_t)g * INTER + nt * 128 + (c & 31) * 4,
                 (char*)lds + 49152 + q * 4096 + wave * 1024);
  }
#pragma unroll
  for (int q = 0; q < 2; ++q) {                 // zeros 2KB: 2x4B/thread
    const int c = q * 256 + tid;                // 0..511
    const unsigned int* zp = q ? uz : gz;       // mat = c>>8 = q
    const int g = (c >> 4) & 15;
    async_copy4(zp + (size_t)g * (INTER / 8) + nt * 16 + (c & 15),
                (char*)lds + 65536 + q * 1024 + wave * 256);
  }
  GU_LOADB(bqE, 0); GU_STAGE_A(0, 0);
  GU_LOADB(bqO, 1); GU_STAGE_A(1, 1);
  WAITVM(12);   // scl+zer+tile0 resident; tile1 (B 8 + A 4) in flight
  BAR; SB0;

  int cur = 0, stg = 2;
  for (int k2 = 0; k2 < 16; ++k2) {
    GU_KIT(2 * k2,     bqE);
    GU_KIT(2 * k2 + 1, bqO);
  }
  WAITVM(0);    // drain clamped dummy prefetches before teardown

  // ---- epilogue: in-wave silu(g)*u -> hs staged [T/128][I/8][128][8] ----
#pragma unroll
  for (int mi = 0; mi < 8; ++mi)
#pragma unroll
    for (int ni = 0; ni < 2; ++ni) {
      const int kg = nt * 128 + wn * 32 + ni * 16 + col;
      const size_t base = (size_t)(mt * 704 + (kg >> 3)) * 1024 + (kg & 7);
#pragma unroll
      for (int r = 0; r < 4; ++r) {
        const float g = accg[mi][ni][r], u = accu[mi][ni][r];
        const float h = g / (1.f + __expf(-g)) * u;
        const int ml = mi * 16 + row16 * 4 + r;
        hs[base + (size_t)ml * 8] = (_Float16)h;
      }
    }
#undef GU_LOADB
#undef GU_STAGE_A
#undef GU_BUILDSC
#undef GU_KIT
}

// ---------------- GEMM2: 8-phase counted-vmcnt, tile 256x256 (proven, unchanged) ----------------
__global__ __launch_bounds__(512, 1)
void k_gemm_down(const _Float16* __restrict__ hs,
                 const _Float16* __restrict__ wd,
                 float* __restrict__ out) {
  extern __shared__ _Float16 lds[];
  _Float16* A0 = lds;            // [2 half][8 kb][128][8] = 16384 f16
  _Float16* A1 = lds + 16384;
  _Float16* B0 = lds + 32768;    // [8 kb][256][8] = 16384 f16
  _Float16* B1 = lds + 49152;

  const int bid  = blockIdx.x;                   // 256 = 8*32, %8==0
  const int wgid = (bid & 7) * 32 + (bid >> 3);  // XCD-chunked swizzle
  const int nt = wgid >> 5, mt = wgid & 31;      // each XCD owns one B-panel (L2-fit)

  const int tid  = threadIdx.x;
  const int wave = tid >> 6, lane = tid & 63;
  const int wm = wave >> 2, wn = wave & 3;       // 2M x 4N
  const int row16 = lane >> 4, col = lane & 15;

  int afo[8], bfo[4];
#pragma unroll
  for (int i = 0; i < 8; ++i)
    afo[i] = wm * 8192 + row16 * 1024 + (i * 16 + col) * 8;
#pragma unroll
  for (int i = 0; i < 4; ++i)
    bfo[i] = row16 * 2048 + (wn * 64 + i * 16 + col) * 8;

  const f32x4 zero = {0.f, 0.f, 0.f, 0.f};
  f32x4 acc[8][4];
#pragma unroll
  for (int i = 0; i < 8; ++i)
#pragma unroll
    for (int j = 0; j < 4; ++j) acc[i][j] = zero;

  f16x8 af[4][2], bf[4][2];

#define DN_LOAD_A(AP, mh) \
  _Pragma("unroll") for (int mi_ = 0; mi_ < 4; ++mi_) \
  _Pragma("unroll") for (int ks_ = 0; ks_ < 2; ++ks_) \
    af[mi_][ks_] = *(const f16x8*)((AP) + afo[(mh) * 4 + mi_] + ks_ * 4096);

#define DN_LOAD_B(BP, nh) \
  _Pragma("unroll") for (int ni_ = 0; ni_ < 2; ++ni_) \
  _Pragma("unroll") for (int ks_ = 0; ks_ < 2; ++ks_) \
    bf[(nh) * 2 + ni_][ks_] = *(const f16x8*)((BP) + bfo[(nh) * 2 + ni_] + ks_ * 8192);

#define DN_MFMA(mh, nh) \
  _Pragma("unroll") for (int mi_ = 0; mi_ < 4; ++mi_) \
  _Pragma("unroll") for (int ni_ = 0; ni_ < 2; ++ni_) \
  _Pragma("unroll") for (int ks_ = 0; ks_ < 2; ++ks_) \
    acc[(mh) * 4 + mi_][(nh) * 2 + ni_] = __builtin_amdgcn_mfma_f32_16x16x32_f16( \
        af[mi_][ks_], bf[(nh) * 2 + ni_][ks_], acc[(mh) * 4 + mi_][(nh) * 2 + ni_], 0, 0, 0);

#define DN_STAGE_A(AP, kt) do { const int kt_ = (kt); \
  _Pragma("unroll") for (int q_ = 0; q_ < 4; ++q_) { \
    const int i_ = q_ * 512 + tid; \
    async_copy16(hs + (size_t)(((2 * mt + (i_ >> 10)) * 704 + kt_ * 8 + ((i_ >> 7) & 7)) * 128 + (i_ & 127)) * 8, \
                 (char*)(AP) + q_ * 8192 + wave * 1024); } } while (0)

#define DN_STAGE_B(BP, kt) do { const int kt_ = (kt); \
  _Pragma("unroll") for (int q_ = 0; q_ < 4; ++q_) { \
    const int i_ = q_ * 512 + tid; \
    async_copy16(wd + (size_t)((kt_ * 8 + (i_ >> 8)) * HIDDEN + nt * 256 + (i_ & 255)) * 8, \
                 (char*)(BP) + q_ * 8192 + wave * 1024); } } while (0)

  // prologue: tile0 -> buf0 (8 loads), tile1 -> buf1 (8 loads)
  DN_STAGE_B(B0, 0); DN_STAGE_A(A0, 0);
  DN_STAGE_B(B1, 1); DN_STAGE_A(A1, 1);
  WAITVM(8);          // tile0 complete; tile1's 8 stay in flight
  BAR; SB0;

  for (int t2 = 0; t2 < 44; ++t2) {
    const int e2 = (2 * t2 + 2 < 88) ? 2 * t2 + 2 : 87;
    const int o2 = (2 * t2 + 3 < 88) ? 2 * t2 + 3 : 87;
    // ph1: E Q(0,0)
    DN_LOAD_A(A0, 0); DN_LOAD_B(B0, 0);
    BAR; LGKM0; PRIO(1); DN_MFMA(0, 0); PRIO(0); BAR; SB0;
    // ph2: E Q(0,1)
    DN_LOAD_B(B0, 1);
    BAR; LGKM0; PRIO(1); DN_MFMA(0, 1); PRIO(0); BAR; SB0;
    // ph3: E Q(1,0)
    DN_LOAD_A(A0, 1); DN_STAGE_B(B0, e2);
    BAR; LGKM0; PRIO(1); DN_MFMA(1, 0); PRIO(0); BAR; SB0;
    // ph4: E Q(1,1) + counted wait (tile O resident)
    DN_STAGE_A(A0, e2);
    BAR; LGKM0; PRIO(1); DN_MFMA(1, 1); PRIO(0); WAITVM(8); BAR; SB0;
    // ph5: O Q(0,0)
    DN_LOAD_A(A1, 0); DN_LOAD_B(B1, 0);
    BAR; LGKM0; PRIO(1); DN_MFMA(0, 0); PRIO(0); BAR; SB0;
    // ph6: O Q(0,1)
    DN_LOAD_B(B1, 1);
    BAR; LGKM0; PRIO(1); DN_MFMA(0, 1); PRIO(0); BAR; SB0;
    // ph7: O Q(1,0)
    DN_LOAD_A(A1, 1); DN_STAGE_B(B1, o2);
    BAR; LGKM0; PRIO(1); DN_MFMA(1, 0); PRIO(0); BAR; SB0;
    // ph8: O Q(1,1) + counted wait (tile E+2 resident)
    DN_STAGE_A(A1, o2);
    BAR; LGKM0; PRIO(1); DN_MFMA(1, 1); PRIO(0); WAITVM(8); BAR; SB0;
  }
  WAITVM(0);

#pragma unroll
  for (int mi = 0; mi < 8; ++mi)
#pragma unroll
    for (int ni = 0; ni < 4; ++ni) {
      const int n = nt * 256 + wn * 64 + ni * 16 + col;
#pragma unroll
      for (int r = 0; r < 4; ++r) {
        const int m = mt * 256 + wm * 128 + mi * 16 + row16 * 4 + r;
        out[(size_t)m * HIDDEN + n] = acc[mi][ni][r];
      }
    }
#undef DN_LOAD_A
#undef DN_LOAD_B
#undef DN_MFMA
#undef DN_STAGE_A
#undef DN_STAGE_B
}

extern "C" void kernel_launch(void* const* d_in, const int* in_sizes, int n_in,
                              void* d_out, int out_size, void* d_ws, size_t ws_size,
                              hipStream_t stream) {
  (void)in_sizes; (void)n_in; (void)out_size; (void)ws_size;
  const float*        x  = (const float*)d_in[0];
  const unsigned int* gq = (const unsigned int*)d_in[1];
  const unsigned int* gz = (const unsigned int*)d_in[2];
  const float*        gs = (const float*)d_in[3];
  const unsigned int* uq = (const unsigned int*)d_in[4];
  const unsigned int* uz = (const unsigned int*)d_in[5];
  const float*        us = (const float*)d_in[6];
  const unsigned int* dq = (const unsigned int*)d_in[7];
  const unsigned int* dz = (const unsigned int*)d_in[8];
  const float*        ds = (const float*)d_in[9];
  float* out = (float*)d_out;

  // workspace layout (bytes):
  // xs  [0, 32MB)      x staged f16 (k-permuted within 8-groups)
  // wdd [32MB, +23MB)  dequanted down weights, staged f16
  // hs  [+55MB)        h staged f16   -> total ~147MB
  char* ws = (char*)d_ws;
  _Float16* xs  = (_Float16*)ws;
  _Float16* wdd = (_Float16*)(ws + (size_t)TOKENS * HIDDEN * 2);
  _Float16* hs  = wdd + (size_t)INTER * HIDDEN;

  static bool attr_set = false;
  if (!attr_set) {
    hipFuncSetAttribute((const void*)k_gemm_gateup,
                        hipFuncAttributeMaxDynamicSharedMemorySize, 67584);
    hipFuncSetAttribute((const void*)k_gemm_down,
                        hipFuncAttributeMaxDynamicSharedMemorySize, 131072);
    attr_set = true;
  }

  k_convert_x<<<dim3(HIDDEN / 64, TOKENS / 32), 256, 0, stream>>>(x, xs);
  k_dequant<<<dim3(HIDDEN / 256, INTER / 8), 256, 0, stream>>>(dq, dz, ds, wdd, HIDDEN, HIDDEN / 8);
  k_gemm_gateup<<<dim3(INTER / 128, TOKENS / 128), 256, 67584, stream>>>(
      xs, gq, gz, gs, uq, uz, us, hs);
  k_gemm_down<<<dim3(256), 512, 131072, stream>>>(hs, wdd, out);
}